// Round 14
// baseline (595.919 us; speedup 1.0000x reference)
//
#include <hip/hip_runtime.h>
#include <math.h>

#define N_NODES 50000
#define E_EDGES 250000
#define ETOT    300000   // E + N self loops
#define B_G     64
#define NHEAD1  4
#define C1      64
#define D1      256      // NHEAD1*C1
#define C2      64
#define NEG     0.2f

__device__ __forceinline__ float leaky(float v){ return v >= 0.f ? v : NEG * v; }
__device__ __forceinline__ float elu_f(float v){ return v > 0.f ? v : expm1f(v); }

__device__ __forceinline__ float wave_sum(float c){
    #pragma unroll
    for (int off = 32; off > 0; off >>= 1) c += __shfl_xor(c, off, 64);
    return c;
}

// online-softmax update, exactly one exp per edge.
// When c > m: new max; exp(c - c) == 1 so the new term's weight is 1.
__device__ __forceinline__ void osm_update(float c, float xv, float& m, float& s, float& acc){
    if (c > m){
        float sc = __expf(m - c);     // m=-inf first edge -> 0: s=1, acc=xv
        s   = s * sc + 1.f;
        acc = acc * sc + xv;
        m = c;
    } else {
        float w = __expf(c - m);
        s   += w;
        acc += w * xv;
    }
}

// ---------------- init ----------------
__global__ void k_init(int* deg){
    int i = blockIdx.x * 256 + threadIdx.x;
    if (i < N_NODES) deg[i] = 0;
}

// ---------------- conv1 linear (K=5) ----------------
__global__ void k_lin1(const float* __restrict__ x,
                       const float* __restrict__ Wl, const float* __restrict__ bl,
                       const float* __restrict__ Wr, const float* __restrict__ br,
                       float* __restrict__ xl, float* __restrict__ xr){
    int n = blockIdx.x;          // node
    int o = threadIdx.x;         // 0..255
    float x0 = x[n*5+0], x1 = x[n*5+1], x2 = x[n*5+2], x3 = x[n*5+3], x4 = x[n*5+4];
    float vl = bl[o] + x0*Wl[o] + x1*Wl[256+o] + x2*Wl[512+o] + x3*Wl[768+o] + x4*Wl[1024+o];
    float vr = br[o] + x0*Wr[o] + x1*Wr[256+o] + x2*Wr[512+o] + x3*Wr[768+o] + x4*Wr[1024+o];
    int idx = n * D1 + o;
    xl[idx] = vl;
    xr[idx] = vr;
}

// ---------------- CSR build ----------------
__global__ void k_deg(const int* __restrict__ ei, int* __restrict__ deg){
    int e = blockIdx.x * 256 + threadIdx.x;
    if (e >= ETOT) return;
    int dst = (e < E_EDGES) ? ei[E_EDGES + e] : (e - E_EDGES);
    atomicAdd(&deg[dst], 1);
}

__global__ void k_scan(const int* __restrict__ deg, int* __restrict__ row_ptr, int* __restrict__ cursor){
    __shared__ int part[1024];
    int t = threadIdx.x;
    const int CH = (N_NODES + 1023) / 1024;
    int base = t * CH;
    int s = 0;
    for (int k = 0; k < CH; k++){ int i = base + k; if (i < N_NODES) s += deg[i]; }
    part[t] = s;
    __syncthreads();
    for (int off = 1; off < 1024; off <<= 1){
        int v = (t >= off) ? part[t - off] : 0;
        __syncthreads();
        part[t] += v;
        __syncthreads();
    }
    int run = (t == 0) ? 0 : part[t - 1];
    for (int k = 0; k < CH; k++){
        int i = base + k;
        if (i < N_NODES){ row_ptr[i] = run; cursor[i] = run; run += deg[i]; }
    }
    if (t == 1023) row_ptr[N_NODES] = part[1023];
}

__global__ void k_fill(const int* __restrict__ ei, int* __restrict__ cursor,
                       int* __restrict__ csr_src){
    int e = blockIdx.x * 256 + threadIdx.x;
    if (e >= ETOT) return;
    int src, dst;
    if (e < E_EDGES){ src = ei[e]; dst = ei[E_EDGES + e]; }
    else            { src = dst = e - E_EDGES; }
    int pos = atomicAdd(&cursor[dst], 1);
    csr_src[pos] = src;
}

// ---------------- conv1 fused, 4x unrolled edge loop ----------------
// One block (256 thr = 4 waves) per dst node; wave h owns head h.
__global__ void k_conv1(const int* __restrict__ row_ptr, const int* __restrict__ csr_src,
                        const float* __restrict__ xl, const float* __restrict__ xr,
                        const float* __restrict__ att, const float* __restrict__ bias,
                        float* __restrict__ hout){
    int nd = blockIdx.x;
    int t = threadIdx.x;          // channel 0..255
    int beg = row_ptr[nd], end = row_ptr[nd + 1];
    float xr_v  = xr[(size_t)nd * D1 + t];
    float att_v = att[t];
    float m = -INFINITY, s = 0.f, acc = 0.f;
    int k = beg;
    for (; k + 3 < end; k += 4){
        int i0 = csr_src[k], i1 = csr_src[k+1], i2 = csr_src[k+2], i3 = csr_src[k+3];
        float x0 = xl[(size_t)i0 * D1 + t];
        float x1 = xl[(size_t)i1 * D1 + t];
        float x2 = xl[(size_t)i2 * D1 + t];
        float x3 = xl[(size_t)i3 * D1 + t];
        float c0 = leaky(x0 + xr_v) * att_v;
        float c1 = leaky(x1 + xr_v) * att_v;
        float c2 = leaky(x2 + xr_v) * att_v;
        float c3 = leaky(x3 + xr_v) * att_v;
        #pragma unroll
        for (int off = 32; off > 0; off >>= 1){   // 4 independent butterflies -> ILP
            c0 += __shfl_xor(c0, off, 64);
            c1 += __shfl_xor(c1, off, 64);
            c2 += __shfl_xor(c2, off, 64);
            c3 += __shfl_xor(c3, off, 64);
        }
        osm_update(c0, x0, m, s, acc);
        osm_update(c1, x1, m, s, acc);
        osm_update(c2, x2, m, s, acc);
        osm_update(c3, x3, m, s, acc);
    }
    for (; k < end; k++){
        int i0 = csr_src[k];
        float x0 = xl[(size_t)i0 * D1 + t];
        float c0 = wave_sum(leaky(x0 + xr_v) * att_v);
        osm_update(c0, x0, m, s, acc);
    }
    hout[(size_t)nd * D1 + t] = elu_f(acc / s + bias[t]);
}

// ---------------- conv2 linear (K=256), 16 nodes/block, l+r fused per thread ----------------
#define LIN2_NB 16
__global__ void k_lin2(const float* __restrict__ h1,
                       const float* __restrict__ Wl, const float* __restrict__ bl,
                       const float* __restrict__ Wr, const float* __restrict__ br,
                       float* __restrict__ xl2, float* __restrict__ xr2){
    __shared__ float rows[LIN2_NB * D1];   // 16 KB, [node][k]
    int base = blockIdx.x * LIN2_NB;
    int t = threadIdx.x;                   // 0..127 (2 waves)
    const float4* src4 = (const float4*)(h1 + (size_t)base * D1);
    float4* dst4 = (float4*)rows;
    for (int i = t; i < LIN2_NB * D1 / 4; i += 128) dst4[i] = src4[i];
    __syncthreads();

    int c  = t & 63;            // output channel
    int ng = t >> 6;            // node group 0..1 -> nodes ng*8 .. ng*8+7
    float accl[8], accr[8];
    float blv = bl[c], brv = br[c];
    #pragma unroll
    for (int j = 0; j < 8; j++){ accl[j] = blv; accr[j] = brv; }
    const float* rowbase = rows + (ng * 8) * D1;
    for (int k = 0; k < D1; k++){
        float wl = Wl[k * 64 + c];
        float wr = Wr[k * 64 + c];
        #pragma unroll
        for (int j = 0; j < 8; j++){
            float hv = rowbase[j * D1 + k];   // broadcast within wave; b128 after k-unroll
            accl[j] += hv * wl;
            accr[j] += hv * wr;
        }
    }
    #pragma unroll
    for (int j = 0; j < 8; j++){
        int node = base + ng * 8 + j;
        xl2[(size_t)node * 64 + c] = accl[j];
        xr2[(size_t)node * 64 + c] = accr[j];
    }
}

// ---------------- conv2 fused (H=1): one wave per node, 4x unrolled ----------------
__global__ void k_conv2(const int* __restrict__ row_ptr, const int* __restrict__ csr_src,
                        const float* __restrict__ xl2, const float* __restrict__ xr2,
                        const float* __restrict__ att, const float* __restrict__ bias,
                        float* __restrict__ hout){
    int w    = threadIdx.x >> 6;   // wave 0..3
    int lane = threadIdx.x & 63;   // channel
    int nd = blockIdx.x * 4 + w;
    if (nd >= N_NODES) return;
    int beg = row_ptr[nd], end = row_ptr[nd + 1];
    float xr_v  = xr2[(size_t)nd * C2 + lane];
    float att_v = att[lane];
    float m = -INFINITY, s = 0.f, acc = 0.f;
    int k = beg;
    for (; k + 3 < end; k += 4){
        int i0 = csr_src[k], i1 = csr_src[k+1], i2 = csr_src[k+2], i3 = csr_src[k+3];
        float x0 = xl2[(size_t)i0 * C2 + lane];
        float x1 = xl2[(size_t)i1 * C2 + lane];
        float x2 = xl2[(size_t)i2 * C2 + lane];
        float x3 = xl2[(size_t)i3 * C2 + lane];
        float c0 = leaky(x0 + xr_v) * att_v;
        float c1 = leaky(x1 + xr_v) * att_v;
        float c2 = leaky(x2 + xr_v) * att_v;
        float c3 = leaky(x3 + xr_v) * att_v;
        #pragma unroll
        for (int off = 32; off > 0; off >>= 1){
            c0 += __shfl_xor(c0, off, 64);
            c1 += __shfl_xor(c1, off, 64);
            c2 += __shfl_xor(c2, off, 64);
            c3 += __shfl_xor(c3, off, 64);
        }
        osm_update(c0, x0, m, s, acc);
        osm_update(c1, x1, m, s, acc);
        osm_update(c2, x2, m, s, acc);
        osm_update(c3, x3, m, s, acc);
    }
    for (; k < end; k++){
        int i0 = csr_src[k];
        float x0 = xl2[(size_t)i0 * C2 + lane];
        float c0 = wave_sum(leaky(x0 + xr_v) * att_v);
        osm_update(c0, x0, m, s, acc);
    }
    hout[(size_t)nd * C2 + lane] = elu_f(acc / s + bias[lane]);
}

// ---------------- pooling: one block per graph, zero atomics ----------------
__device__ __forceinline__ int lower_bound_batch(const int* __restrict__ batch, int val){
    int lo = 0, hi = N_NODES;
    while (lo < hi){ int mid = (lo + hi) >> 1; if (batch[mid] < val) lo = mid + 1; else hi = mid; }
    return lo;
}

__global__ void k_pool(const float* __restrict__ h2, const int* __restrict__ batch,
                       float* __restrict__ pool_sum, float* __restrict__ pool_max,
                       int* __restrict__ pool_cnt){
    __shared__ float ssum[256], smax[256];
    int b = blockIdx.x;            // graph id
    int t = threadIdx.x;           // 0..255
    int lo = lower_bound_batch(batch, b);
    int hi = lower_bound_batch(batch, b + 1);
    int c = t & 63;                // channel
    int j = t >> 6;                // node slice 0..3
    float s = 0.f, mx = -INFINITY;
    for (int nd = lo + j; nd < hi; nd += 4){
        float v = h2[(size_t)nd * C2 + c];
        s += v;
        mx = fmaxf(mx, v);
    }
    ssum[t] = s; smax[t] = mx;
    __syncthreads();
    if (t < 128){ ssum[t] += ssum[t + 128]; smax[t] = fmaxf(smax[t], smax[t + 128]); }
    __syncthreads();
    if (t < 64){
        pool_sum[b * C2 + t] = ssum[t] + ssum[t + 64];
        pool_max[b * C2 + t] = fmaxf(smax[t], smax[t + 64]);
    }
    if (t == 0) pool_cnt[b] = hi - lo;
}

// ---------------- final linear [B,192]@[192,2] ----------------
__global__ void k_final(const float* __restrict__ pool_sum, const float* __restrict__ pool_max,
                        const int* __restrict__ pool_cnt,
                        const float* __restrict__ Wlin, const float* __restrict__ blin,
                        float* __restrict__ out){
    int t = threadIdx.x;
    if (t >= B_G * 2) return;
    int b = t >> 1, o = t & 1;
    float cnt = fmaxf((float)pool_cnt[b], 1.f);
    float acc = blin[o];
    for (int j = 0; j < C2; j++){
        float sm = pool_sum[b * C2 + j];
        float mx = pool_max[b * C2 + j];
        acc += (sm / cnt) * Wlin[j * 2 + o];
        acc += mx * Wlin[(C2 + j) * 2 + o];
        acc += sm * Wlin[(2 * C2 + j) * 2 + o];
    }
    out[b * 2 + o] = acc;
}

extern "C" void kernel_launch(void* const* d_in, const int* in_sizes, int n_in,
                              void* d_out, int out_size, void* d_ws, size_t ws_size,
                              hipStream_t stream) {
    const float* x     = (const float*)d_in[0];
    const int*   ei    = (const int*)d_in[1];
    const int*   batch = (const int*)d_in[2];
    const float* Wl1   = (const float*)d_in[3];
    const float* bl1   = (const float*)d_in[4];
    const float* Wr1   = (const float*)d_in[5];
    const float* br1   = (const float*)d_in[6];
    const float* att1  = (const float*)d_in[7];
    const float* bias1 = (const float*)d_in[8];
    const float* Wl2   = (const float*)d_in[9];
    const float* bl2   = (const float*)d_in[10];
    const float* Wr2   = (const float*)d_in[11];
    const float* br2   = (const float*)d_in[12];
    const float* att2  = (const float*)d_in[13];
    const float* bias2 = (const float*)d_in[14];
    const float* Wlin  = (const float*)d_in[15];
    const float* blin  = (const float*)d_in[16];
    float* out = (float*)d_out;

    char* w = (char*)d_ws;
    float* bufA = (float*)w;  w += (size_t)N_NODES * D1 * 4;   // xl1 ; later xl2|xr2
    float* bufB = (float*)w;  w += (size_t)N_NODES * D1 * 4;   // xr1 -> h1 ; later h2
    int* deg    = (int*)w;    w += (size_t)N_NODES * 4;
    int* row_ptr= (int*)w;    w += (size_t)(N_NODES + 1) * 4;
    int* cursor = (int*)w;    w += (size_t)N_NODES * 4;
    int* csr_src= (int*)w;    w += (size_t)ETOT * 4;
    float* pool_sum = (float*)w;  w += (size_t)B_G * C2 * 4;
    float* pool_max = (float*)w;  w += (size_t)B_G * C2 * 4;
    int*   pool_cnt = (int*)w;    w += (size_t)B_G * 4;

    float* xl1 = bufA;
    float* xr1 = bufB;
    float* h1  = bufB;                              // conv1 writes over xr1 (safe: dst-indexed)
    float* xl2 = bufA;                              // overwrites xl1 (dead after conv1)
    float* xr2 = bufA + (size_t)N_NODES * C2;
    float* h2  = bufB;                              // overwrites h1 (dead after lin2)

    // init deg
    k_init<<<(N_NODES + 255) / 256, 256, 0, stream>>>(deg);
    // conv1 linear
    k_lin1<<<N_NODES, 256, 0, stream>>>(x, Wl1, bl1, Wr1, br1, xl1, xr1);
    // CSR build (shared by both convs)
    k_deg<<<(ETOT + 255) / 256, 256, 0, stream>>>(ei, deg);
    k_scan<<<1, 1024, 0, stream>>>(deg, row_ptr, cursor);
    k_fill<<<(ETOT + 255) / 256, 256, 0, stream>>>(ei, cursor, csr_src);
    // conv1 fused (att + softmax + agg + ELU)
    k_conv1<<<N_NODES, 256, 0, stream>>>(row_ptr, csr_src, xl1, xr1, att1, bias1, h1);
    // conv2
    k_lin2<<<N_NODES / LIN2_NB, 128, 0, stream>>>(h1, Wl2, bl2, Wr2, br2, xl2, xr2);
    k_conv2<<<(N_NODES + 3) / 4, 256, 0, stream>>>(row_ptr, csr_src, xl2, xr2, att2, bias2, h2);
    // pooling (atomic-free) + head
    k_pool<<<B_G, 256, 0, stream>>>(h2, batch, pool_sum, pool_max, pool_cnt);
    k_final<<<1, 128, 0, stream>>>(pool_sum, pool_max, pool_cnt, Wlin, blin, out);
}

// Round 15
// 529.994 us; speedup vs baseline: 1.1244x; 1.1244x over previous
//
#include <hip/hip_runtime.h>
#include <math.h>

#define N_NODES 50000
#define E_EDGES 250000
#define ETOT    300000   // E + N self loops
#define B_G     64
#define NHEAD1  4
#define C1      64
#define D1      256      // NHEAD1*C1
#define C2      64
#define NEG     0.2f

__device__ __forceinline__ float leaky(float v){ return v >= 0.f ? v : NEG * v; }
__device__ __forceinline__ float elu_f(float v){ return v > 0.f ? v : expm1f(v); }

__device__ __forceinline__ float wave_sum(float c){
    #pragma unroll
    for (int off = 32; off > 0; off >>= 1) c += __shfl_xor(c, off, 64);
    return c;
}

// online-softmax update, exactly one exp per edge.
__device__ __forceinline__ void osm_update(float c, float xv, float& m, float& s, float& acc){
    if (c > m){
        float sc = __expf(m - c);     // m=-inf first edge -> 0: s=1, acc=xv
        s   = s * sc + 1.f;
        acc = acc * sc + xv;
        m = c;
    } else {
        float w = __expf(c - m);
        s   += w;
        acc += w * xv;
    }
}

// ---------------- init ----------------
__global__ void k_init(int* deg){
    int i = blockIdx.x * 256 + threadIdx.x;
    if (i < N_NODES) deg[i] = 0;
}

// ---------------- conv1 linear (K=5) ----------------
__global__ void k_lin1(const float* __restrict__ x,
                       const float* __restrict__ Wl, const float* __restrict__ bl,
                       const float* __restrict__ Wr, const float* __restrict__ br,
                       float* __restrict__ xl, float* __restrict__ xr){
    int n = blockIdx.x;          // node
    int o = threadIdx.x;         // 0..255
    float x0 = x[n*5+0], x1 = x[n*5+1], x2 = x[n*5+2], x3 = x[n*5+3], x4 = x[n*5+4];
    float vl = bl[o] + x0*Wl[o] + x1*Wl[256+o] + x2*Wl[512+o] + x3*Wl[768+o] + x4*Wl[1024+o];
    float vr = br[o] + x0*Wr[o] + x1*Wr[256+o] + x2*Wr[512+o] + x3*Wr[768+o] + x4*Wr[1024+o];
    int idx = n * D1 + o;
    xl[idx] = vl;
    xr[idx] = vr;
}

// ---------------- CSR build ----------------
__global__ void k_deg(const int* __restrict__ ei, int* __restrict__ deg){
    int e = blockIdx.x * 256 + threadIdx.x;
    if (e >= ETOT) return;
    int dst = (e < E_EDGES) ? ei[E_EDGES + e] : (e - E_EDGES);
    atomicAdd(&deg[dst], 1);
}

__global__ void k_scan(const int* __restrict__ deg, int* __restrict__ row_ptr, int* __restrict__ cursor){
    __shared__ int part[1024];
    int t = threadIdx.x;
    const int CH = (N_NODES + 1023) / 1024;
    int base = t * CH;
    int s = 0;
    for (int k = 0; k < CH; k++){ int i = base + k; if (i < N_NODES) s += deg[i]; }
    part[t] = s;
    __syncthreads();
    for (int off = 1; off < 1024; off <<= 1){
        int v = (t >= off) ? part[t - off] : 0;
        __syncthreads();
        part[t] += v;
        __syncthreads();
    }
    int run = (t == 0) ? 0 : part[t - 1];
    for (int k = 0; k < CH; k++){
        int i = base + k;
        if (i < N_NODES){ row_ptr[i] = run; cursor[i] = run; run += deg[i]; }
    }
    if (t == 1023) row_ptr[N_NODES] = part[1023];
}

__global__ void k_fill(const int* __restrict__ ei, int* __restrict__ cursor,
                       int* __restrict__ csr_src){
    int e = blockIdx.x * 256 + threadIdx.x;
    if (e >= ETOT) return;
    int src, dst;
    if (e < E_EDGES){ src = ei[e]; dst = ei[E_EDGES + e]; }
    else            { src = dst = e - E_EDGES; }
    int pos = atomicAdd(&cursor[dst], 1);
    csr_src[pos] = src;
}

// ---------------- conv1 fused, 4x unrolled edge loop ----------------
// One block (256 thr = 4 waves) per dst node; wave h owns head h.
__global__ void k_conv1(const int* __restrict__ row_ptr, const int* __restrict__ csr_src,
                        const float* __restrict__ xl, const float* __restrict__ xr,
                        const float* __restrict__ att, const float* __restrict__ bias,
                        float* __restrict__ hout){
    int nd = blockIdx.x;
    int t = threadIdx.x;          // channel 0..255
    int beg = row_ptr[nd], end = row_ptr[nd + 1];
    float xr_v  = xr[(size_t)nd * D1 + t];
    float att_v = att[t];
    float m = -INFINITY, s = 0.f, acc = 0.f;
    int k = beg;
    for (; k + 3 < end; k += 4){
        int i0 = csr_src[k], i1 = csr_src[k+1], i2 = csr_src[k+2], i3 = csr_src[k+3];
        float x0 = xl[(size_t)i0 * D1 + t];
        float x1 = xl[(size_t)i1 * D1 + t];
        float x2 = xl[(size_t)i2 * D1 + t];
        float x3 = xl[(size_t)i3 * D1 + t];
        float c0 = leaky(x0 + xr_v) * att_v;
        float c1 = leaky(x1 + xr_v) * att_v;
        float c2 = leaky(x2 + xr_v) * att_v;
        float c3 = leaky(x3 + xr_v) * att_v;
        #pragma unroll
        for (int off = 32; off > 0; off >>= 1){   // 4 independent butterflies -> ILP
            c0 += __shfl_xor(c0, off, 64);
            c1 += __shfl_xor(c1, off, 64);
            c2 += __shfl_xor(c2, off, 64);
            c3 += __shfl_xor(c3, off, 64);
        }
        osm_update(c0, x0, m, s, acc);
        osm_update(c1, x1, m, s, acc);
        osm_update(c2, x2, m, s, acc);
        osm_update(c3, x3, m, s, acc);
    }
    for (; k < end; k++){
        int i0 = csr_src[k];
        float x0 = xl[(size_t)i0 * D1 + t];
        float c0 = wave_sum(leaky(x0 + xr_v) * att_v);
        osm_update(c0, x0, m, s, acc);
    }
    hout[(size_t)nd * D1 + t] = elu_f(acc / s + bias[t]);
}

// ---------------- conv2 linear (K=256), 16 nodes/block, 256 thr, float4 LDS reads ----------------
#define LIN2_NB 16
__global__ void k_lin2(const float* __restrict__ h1,
                       const float* __restrict__ Wl, const float* __restrict__ bl,
                       const float* __restrict__ Wr, const float* __restrict__ br,
                       float* __restrict__ xl2, float* __restrict__ xr2){
    __shared__ float rows[LIN2_NB * D1];   // 16 KB, [node][k]
    int base = blockIdx.x * LIN2_NB;       // first node of this block
    int t = threadIdx.x;                   // 0..255 (4 waves)
    const float4* src4 = (const float4*)(h1 + (size_t)base * D1);
    float4* dst4 = (float4*)rows;
    for (int i = t; i < LIN2_NB * D1 / 4; i += 256) dst4[i] = src4[i];
    __syncthreads();

    int c     = t & 63;         // output channel
    int which = (t >> 6) & 1;   // 0 = l, 1 = r
    int ng    = t >> 7;         // node group 0..1 -> rows ng*8 .. ng*8+7
    const float* W = which ? Wr : Wl;
    float bias = which ? br[c] : bl[c];
    float acc[8];
    #pragma unroll
    for (int j = 0; j < 8; j++) acc[j] = bias;

    const float* rowbase = rows + (ng * 8) * D1;
    for (int k = 0; k < D1; k += 4){
        // 4 W values (coalesced 256B per load across the wave; L2-hot)
        float w0 = W[(k + 0) * 64 + c];
        float w1 = W[(k + 1) * 64 + c];
        float w2 = W[(k + 2) * 64 + c];
        float w3 = W[(k + 3) * 64 + c];
        #pragma unroll
        for (int j = 0; j < 8; j++){
            float4 a = *(const float4*)(rowbase + j * D1 + k);   // 1 b128 vs 4 b32
            acc[j] += a.x * w0 + a.y * w1 + a.z * w2 + a.w * w3;
        }
    }
    float* dst = which ? xr2 : xl2;
    #pragma unroll
    for (int j = 0; j < 8; j++){
        int node = base + ng * 8 + j;
        dst[(size_t)node * 64 + c] = acc[j];
    }
}

// ---------------- conv2 fused (H=1): one wave per node, 4x unrolled ----------------
__global__ void k_conv2(const int* __restrict__ row_ptr, const int* __restrict__ csr_src,
                        const float* __restrict__ xl2, const float* __restrict__ xr2,
                        const float* __restrict__ att, const float* __restrict__ bias,
                        float* __restrict__ hout){
    int w    = threadIdx.x >> 6;   // wave 0..3
    int lane = threadIdx.x & 63;   // channel
    int nd = blockIdx.x * 4 + w;
    if (nd >= N_NODES) return;
    int beg = row_ptr[nd], end = row_ptr[nd + 1];
    float xr_v  = xr2[(size_t)nd * C2 + lane];
    float att_v = att[lane];
    float m = -INFINITY, s = 0.f, acc = 0.f;
    int k = beg;
    for (; k + 3 < end; k += 4){
        int i0 = csr_src[k], i1 = csr_src[k+1], i2 = csr_src[k+2], i3 = csr_src[k+3];
        float x0 = xl2[(size_t)i0 * C2 + lane];
        float x1 = xl2[(size_t)i1 * C2 + lane];
        float x2 = xl2[(size_t)i2 * C2 + lane];
        float x3 = xl2[(size_t)i3 * C2 + lane];
        float c0 = leaky(x0 + xr_v) * att_v;
        float c1 = leaky(x1 + xr_v) * att_v;
        float c2 = leaky(x2 + xr_v) * att_v;
        float c3 = leaky(x3 + xr_v) * att_v;
        #pragma unroll
        for (int off = 32; off > 0; off >>= 1){
            c0 += __shfl_xor(c0, off, 64);
            c1 += __shfl_xor(c1, off, 64);
            c2 += __shfl_xor(c2, off, 64);
            c3 += __shfl_xor(c3, off, 64);
        }
        osm_update(c0, x0, m, s, acc);
        osm_update(c1, x1, m, s, acc);
        osm_update(c2, x2, m, s, acc);
        osm_update(c3, x3, m, s, acc);
    }
    for (; k < end; k++){
        int i0 = csr_src[k];
        float x0 = xl2[(size_t)i0 * C2 + lane];
        float c0 = wave_sum(leaky(x0 + xr_v) * att_v);
        osm_update(c0, x0, m, s, acc);
    }
    hout[(size_t)nd * C2 + lane] = elu_f(acc / s + bias[lane]);
}

// ---------------- pooling: one block per graph, zero atomics ----------------
__device__ __forceinline__ int lower_bound_batch(const int* __restrict__ batch, int val){
    int lo = 0, hi = N_NODES;
    while (lo < hi){ int mid = (lo + hi) >> 1; if (batch[mid] < val) lo = mid + 1; else hi = mid; }
    return lo;
}

__global__ void k_pool(const float* __restrict__ h2, const int* __restrict__ batch,
                       float* __restrict__ pool_sum, float* __restrict__ pool_max,
                       int* __restrict__ pool_cnt){
    __shared__ float ssum[256], smax[256];
    int b = blockIdx.x;            // graph id
    int t = threadIdx.x;           // 0..255
    int lo = lower_bound_batch(batch, b);
    int hi = lower_bound_batch(batch, b + 1);
    int c = t & 63;                // channel
    int j = t >> 6;                // node slice 0..3
    float s = 0.f, mx = -INFINITY;
    for (int nd = lo + j; nd < hi; nd += 4){
        float v = h2[(size_t)nd * C2 + c];
        s += v;
        mx = fmaxf(mx, v);
    }
    ssum[t] = s; smax[t] = mx;
    __syncthreads();
    if (t < 128){ ssum[t] += ssum[t + 128]; smax[t] = fmaxf(smax[t], smax[t + 128]); }
    __syncthreads();
    if (t < 64){
        pool_sum[b * C2 + t] = ssum[t] + ssum[t + 64];
        pool_max[b * C2 + t] = fmaxf(smax[t], smax[t + 64]);
    }
    if (t == 0) pool_cnt[b] = hi - lo;
}

// ---------------- final linear [B,192]@[192,2] ----------------
__global__ void k_final(const float* __restrict__ pool_sum, const float* __restrict__ pool_max,
                        const int* __restrict__ pool_cnt,
                        const float* __restrict__ Wlin, const float* __restrict__ blin,
                        float* __restrict__ out){
    int t = threadIdx.x;
    if (t >= B_G * 2) return;
    int b = t >> 1, o = t & 1;
    float cnt = fmaxf((float)pool_cnt[b], 1.f);
    float acc = blin[o];
    for (int j = 0; j < C2; j++){
        float sm = pool_sum[b * C2 + j];
        float mx = pool_max[b * C2 + j];
        acc += (sm / cnt) * Wlin[j * 2 + o];
        acc += mx * Wlin[(C2 + j) * 2 + o];
        acc += sm * Wlin[(2 * C2 + j) * 2 + o];
    }
    out[b * 2 + o] = acc;
}

extern "C" void kernel_launch(void* const* d_in, const int* in_sizes, int n_in,
                              void* d_out, int out_size, void* d_ws, size_t ws_size,
                              hipStream_t stream) {
    const float* x     = (const float*)d_in[0];
    const int*   ei    = (const int*)d_in[1];
    const int*   batch = (const int*)d_in[2];
    const float* Wl1   = (const float*)d_in[3];
    const float* bl1   = (const float*)d_in[4];
    const float* Wr1   = (const float*)d_in[5];
    const float* br1   = (const float*)d_in[6];
    const float* att1  = (const float*)d_in[7];
    const float* bias1 = (const float*)d_in[8];
    const float* Wl2   = (const float*)d_in[9];
    const float* bl2   = (const float*)d_in[10];
    const float* Wr2   = (const float*)d_in[11];
    const float* br2   = (const float*)d_in[12];
    const float* att2  = (const float*)d_in[13];
    const float* bias2 = (const float*)d_in[14];
    const float* Wlin  = (const float*)d_in[15];
    const float* blin  = (const float*)d_in[16];
    float* out = (float*)d_out;

    char* w = (char*)d_ws;
    float* bufA = (float*)w;  w += (size_t)N_NODES * D1 * 4;   // xl1 ; later xl2|xr2
    float* bufB = (float*)w;  w += (size_t)N_NODES * D1 * 4;   // xr1 -> h1 ; later h2
    int* deg    = (int*)w;    w += (size_t)N_NODES * 4;
    int* row_ptr= (int*)w;    w += (size_t)(N_NODES + 1) * 4;
    int* cursor = (int*)w;    w += (size_t)N_NODES * 4;
    int* csr_src= (int*)w;    w += (size_t)ETOT * 4;
    float* pool_sum = (float*)w;  w += (size_t)B_G * C2 * 4;
    float* pool_max = (float*)w;  w += (size_t)B_G * C2 * 4;
    int*   pool_cnt = (int*)w;    w += (size_t)B_G * 4;

    float* xl1 = bufA;
    float* xr1 = bufB;
    float* h1  = bufB;                              // conv1 writes over xr1 (safe: dst-indexed)
    float* xl2 = bufA;                              // overwrites xl1 (dead after conv1)
    float* xr2 = bufA + (size_t)N_NODES * C2;
    float* h2  = bufB;                              // overwrites h1 (dead after lin2)

    // init deg
    k_init<<<(N_NODES + 255) / 256, 256, 0, stream>>>(deg);
    // conv1 linear
    k_lin1<<<N_NODES, 256, 0, stream>>>(x, Wl1, bl1, Wr1, br1, xl1, xr1);
    // CSR build (shared by both convs)
    k_deg<<<(ETOT + 255) / 256, 256, 0, stream>>>(ei, deg);
    k_scan<<<1, 1024, 0, stream>>>(deg, row_ptr, cursor);
    k_fill<<<(ETOT + 255) / 256, 256, 0, stream>>>(ei, cursor, csr_src);
    // conv1 fused (att + softmax + agg + ELU)
    k_conv1<<<N_NODES, 256, 0, stream>>>(row_ptr, csr_src, xl1, xr1, att1, bias1, h1);
    // conv2
    k_lin2<<<N_NODES / LIN2_NB, 256, 0, stream>>>(h1, Wl2, bl2, Wr2, br2, xl2, xr2);
    k_conv2<<<(N_NODES + 3) / 4, 256, 0, stream>>>(row_ptr, csr_src, xl2, xr2, att2, bias2, h2);
    // pooling (atomic-free) + head
    k_pool<<<B_G, 256, 0, stream>>>(h2, batch, pool_sum, pool_max, pool_cnt);
    k_final<<<1, 128, 0, stream>>>(pool_sum, pool_max, pool_cnt, Wlin, blin, out);
}

// Round 18
// 419.546 us; speedup vs baseline: 1.4204x; 1.2633x over previous
//
#include <hip/hip_runtime.h>
#include <math.h>

#define N_NODES 50000
#define E_EDGES 250000
#define ETOT    300000   // E + N self loops
#define B_G     64
#define NHEAD1  4
#define C1      64
#define D1      256      // NHEAD1*C1
#define C2      64
#define NEG     0.2f

#define SCAN_CHUNK 1024
#define SCAN_NB ((N_NODES + SCAN_CHUNK - 1) / SCAN_CHUNK)   // 49

__device__ __forceinline__ float leaky(float v){ return v >= 0.f ? v : NEG * v; }
__device__ __forceinline__ float elu_f(float v){ return v > 0.f ? v : expm1f(v); }

__device__ __forceinline__ float wave_sum(float c){
    #pragma unroll
    for (int off = 32; off > 0; off >>= 1) c += __shfl_xor(c, off, 64);
    return c;
}

// online-softmax update, exactly one exp per edge.
__device__ __forceinline__ void osm_update(float c, float xv, float& m, float& s, float& acc){
    if (c > m){
        float sc = __expf(m - c);     // m=-inf first edge -> 0: s=1, acc=xv
        s   = s * sc + 1.f;
        acc = acc * sc + xv;
        m = c;
    } else {
        float w = __expf(c - m);
        s   += w;
        acc += w * xv;
    }
}

// ---------------- init ----------------
__global__ void k_init(int* deg){
    int i = blockIdx.x * 256 + threadIdx.x;
    if (i < N_NODES) deg[i] = 0;
}

// ---------------- conv1 linear (K=5) ----------------
__global__ void k_lin1(const float* __restrict__ x,
                       const float* __restrict__ Wl, const float* __restrict__ bl,
                       const float* __restrict__ Wr, const float* __restrict__ br,
                       float* __restrict__ xl, float* __restrict__ xr){
    int n = blockIdx.x;          // node
    int o = threadIdx.x;         // 0..255
    float x0 = x[n*5+0], x1 = x[n*5+1], x2 = x[n*5+2], x3 = x[n*5+3], x4 = x[n*5+4];
    float vl = bl[o] + x0*Wl[o] + x1*Wl[256+o] + x2*Wl[512+o] + x3*Wl[768+o] + x4*Wl[1024+o];
    float vr = br[o] + x0*Wr[o] + x1*Wr[256+o] + x2*Wr[512+o] + x3*Wr[768+o] + x4*Wr[1024+o];
    int idx = n * D1 + o;
    xl[idx] = vl;
    xr[idx] = vr;
}

// ---------------- CSR build ----------------
__global__ void k_deg(const int* __restrict__ ei, int* __restrict__ deg){
    int e = blockIdx.x * 256 + threadIdx.x;
    if (e >= ETOT) return;
    int dst = (e < E_EDGES) ? ei[E_EDGES + e] : (e - E_EDGES);
    atomicAdd(&deg[dst], 1);
}

// two-level parallel exclusive scan of deg -> row_ptr / cursor
__global__ void k_scan1(const int* __restrict__ deg, int* __restrict__ part){
    __shared__ int red[256];
    int t = threadIdx.x;
    int base = blockIdx.x * SCAN_CHUNK + t * 4;
    int s = 0;
    #pragma unroll
    for (int j = 0; j < 4; j++){
        int i = base + j;
        if (i < N_NODES) s += deg[i];
    }
    red[t] = s;
    __syncthreads();
    for (int off = 128; off > 0; off >>= 1){
        if (t < off) red[t] += red[t + off];
        __syncthreads();
    }
    if (t == 0) part[blockIdx.x] = red[0];
}

__global__ void k_scan2(int* __restrict__ part){
    __shared__ int tmp[SCAN_NB];
    int t = threadIdx.x;
    if (t < SCAN_NB) tmp[t] = part[t];
    __syncthreads();
    if (t == 0){
        int run = 0;
        for (int i = 0; i < SCAN_NB; i++){ int v = tmp[i]; tmp[i] = run; run += v; }
    }
    __syncthreads();
    if (t < SCAN_NB) part[t] = tmp[t];
}

__global__ void k_scan3(const int* __restrict__ deg, const int* __restrict__ part,
                        int* __restrict__ row_ptr, int* __restrict__ cursor){
    __shared__ int sums[256];
    int t = threadIdx.x;
    int base = blockIdx.x * SCAN_CHUNK + t * 4;
    int d[4]; int ts = 0;
    #pragma unroll
    for (int j = 0; j < 4; j++){
        int i = base + j;
        d[j] = (i < N_NODES) ? deg[i] : 0;
        ts += d[j];
    }
    sums[t] = ts;
    __syncthreads();
    for (int off = 1; off < 256; off <<= 1){   // inclusive Hillis-Steele
        int v = (t >= off) ? sums[t - off] : 0;
        __syncthreads();
        sums[t] += v;
        __syncthreads();
    }
    int prefix = part[blockIdx.x] + ((t == 0) ? 0 : sums[t - 1]);
    #pragma unroll
    for (int j = 0; j < 4; j++){
        int i = base + j;
        if (i < N_NODES){ row_ptr[i] = prefix; cursor[i] = prefix; prefix += d[j]; }
    }
    if (blockIdx.x == 0 && t == 0) row_ptr[N_NODES] = ETOT;   // total is structurally ETOT
}

__global__ void k_fill(const int* __restrict__ ei, int* __restrict__ cursor,
                       int* __restrict__ csr_src){
    int e = blockIdx.x * 256 + threadIdx.x;
    if (e >= ETOT) return;
    int src, dst;
    if (e < E_EDGES){ src = ei[e]; dst = ei[E_EDGES + e]; }
    else            { src = dst = e - E_EDGES; }
    int pos = atomicAdd(&cursor[dst], 1);
    csr_src[pos] = src;
}

// ---------------- conv1 fused, 4x unrolled edge loop ----------------
// One block (256 thr = 4 waves) per dst node; wave h owns head h.
__global__ void k_conv1(const int* __restrict__ row_ptr, const int* __restrict__ csr_src,
                        const float* __restrict__ xl, const float* __restrict__ xr,
                        const float* __restrict__ att, const float* __restrict__ bias,
                        float* __restrict__ hout){
    int nd = blockIdx.x;
    int t = threadIdx.x;          // channel 0..255
    int beg = row_ptr[nd], end = row_ptr[nd + 1];
    float xr_v  = xr[(size_t)nd * D1 + t];
    float att_v = att[t];
    float m = -INFINITY, s = 0.f, acc = 0.f;
    int k = beg;
    for (; k + 3 < end; k += 4){
        int i0 = csr_src[k], i1 = csr_src[k+1], i2 = csr_src[k+2], i3 = csr_src[k+3];
        float x0 = xl[(size_t)i0 * D1 + t];
        float x1 = xl[(size_t)i1 * D1 + t];
        float x2 = xl[(size_t)i2 * D1 + t];
        float x3 = xl[(size_t)i3 * D1 + t];
        float c0 = leaky(x0 + xr_v) * att_v;
        float c1 = leaky(x1 + xr_v) * att_v;
        float c2 = leaky(x2 + xr_v) * att_v;
        float c3 = leaky(x3 + xr_v) * att_v;
        #pragma unroll
        for (int off = 32; off > 0; off >>= 1){   // 4 independent butterflies -> ILP
            c0 += __shfl_xor(c0, off, 64);
            c1 += __shfl_xor(c1, off, 64);
            c2 += __shfl_xor(c2, off, 64);
            c3 += __shfl_xor(c3, off, 64);
        }
        osm_update(c0, x0, m, s, acc);
        osm_update(c1, x1, m, s, acc);
        osm_update(c2, x2, m, s, acc);
        osm_update(c3, x3, m, s, acc);
    }
    for (; k < end; k++){
        int i0 = csr_src[k];
        float x0 = xl[(size_t)i0 * D1 + t];
        float c0 = wave_sum(leaky(x0 + xr_v) * att_v);
        osm_update(c0, x0, m, s, acc);
    }
    hout[(size_t)nd * D1 + t] = elu_f(acc / s + bias[t]);
}

// ---------------- conv2 linear (K=256), 16 nodes/block, 256 thr, float4 LDS reads ----------------
#define LIN2_NB 16
__global__ void k_lin2(const float* __restrict__ h1,
                       const float* __restrict__ Wl, const float* __restrict__ bl,
                       const float* __restrict__ Wr, const float* __restrict__ br,
                       float* __restrict__ xl2, float* __restrict__ xr2){
    __shared__ float rows[LIN2_NB * D1];   // 16 KB, [node][k]
    int base = blockIdx.x * LIN2_NB;       // first node of this block
    int t = threadIdx.x;                   // 0..255 (4 waves)
    const float4* src4 = (const float4*)(h1 + (size_t)base * D1);
    float4* dst4 = (float4*)rows;
    for (int i = t; i < LIN2_NB * D1 / 4; i += 256) dst4[i] = src4[i];
    __syncthreads();

    int c     = t & 63;         // output channel
    int which = (t >> 6) & 1;   // 0 = l, 1 = r
    int ng    = t >> 7;         // node group 0..1 -> rows ng*8 .. ng*8+7
    const float* W = which ? Wr : Wl;
    float bias = which ? br[c] : bl[c];
    float acc[8];
    #pragma unroll
    for (int j = 0; j < 8; j++) acc[j] = bias;

    const float* rowbase = rows + (ng * 8) * D1;
    for (int k = 0; k < D1; k += 4){
        float w0 = W[(k + 0) * 64 + c];
        float w1 = W[(k + 1) * 64 + c];
        float w2 = W[(k + 2) * 64 + c];
        float w3 = W[(k + 3) * 64 + c];
        #pragma unroll
        for (int j = 0; j < 8; j++){
            float4 a = *(const float4*)(rowbase + j * D1 + k);   // 1 b128 vs 4 b32
            acc[j] += a.x * w0 + a.y * w1 + a.z * w2 + a.w * w3;
        }
    }
    float* dst = which ? xr2 : xl2;
    #pragma unroll
    for (int j = 0; j < 8; j++){
        int node = base + ng * 8 + j;
        dst[(size_t)node * 64 + c] = acc[j];
    }
}

// ---------------- conv2 fused (H=1): one wave per node, 4x unrolled ----------------
__global__ void k_conv2(const int* __restrict__ row_ptr, const int* __restrict__ csr_src,
                        const float* __restrict__ xl2, const float* __restrict__ xr2,
                        const float* __restrict__ att, const float* __restrict__ bias,
                        float* __restrict__ hout){
    int w    = threadIdx.x >> 6;   // wave 0..3
    int lane = threadIdx.x & 63;   // channel
    int nd = blockIdx.x * 4 + w;
    if (nd >= N_NODES) return;
    int beg = row_ptr[nd], end = row_ptr[nd + 1];
    float xr_v  = xr2[(size_t)nd * C2 + lane];
    float att_v = att[lane];
    float m = -INFINITY, s = 0.f, acc = 0.f;
    int k = beg;
    for (; k + 3 < end; k += 4){
        int i0 = csr_src[k], i1 = csr_src[k+1], i2 = csr_src[k+2], i3 = csr_src[k+3];
        float x0 = xl2[(size_t)i0 * C2 + lane];
        float x1 = xl2[(size_t)i1 * C2 + lane];
        float x2 = xl2[(size_t)i2 * C2 + lane];
        float x3 = xl2[(size_t)i3 * C2 + lane];
        float c0 = leaky(x0 + xr_v) * att_v;
        float c1 = leaky(x1 + xr_v) * att_v;
        float c2 = leaky(x2 + xr_v) * att_v;
        float c3 = leaky(x3 + xr_v) * att_v;
        #pragma unroll
        for (int off = 32; off > 0; off >>= 1){
            c0 += __shfl_xor(c0, off, 64);
            c1 += __shfl_xor(c1, off, 64);
            c2 += __shfl_xor(c2, off, 64);
            c3 += __shfl_xor(c3, off, 64);
        }
        osm_update(c0, x0, m, s, acc);
        osm_update(c1, x1, m, s, acc);
        osm_update(c2, x2, m, s, acc);
        osm_update(c3, x3, m, s, acc);
    }
    for (; k < end; k++){
        int i0 = csr_src[k];
        float x0 = xl2[(size_t)i0 * C2 + lane];
        float c0 = wave_sum(leaky(x0 + xr_v) * att_v);
        osm_update(c0, x0, m, s, acc);
    }
    hout[(size_t)nd * C2 + lane] = elu_f(acc / s + bias[lane]);
}

// ---------------- pooling: one block per graph, zero atomics ----------------
__device__ __forceinline__ int lower_bound_batch(const int* __restrict__ batch, int val){
    int lo = 0, hi = N_NODES;
    while (lo < hi){ int mid = (lo + hi) >> 1; if (batch[mid] < val) lo = mid + 1; else hi = mid; }
    return lo;
}

__global__ void k_pool(const float* __restrict__ h2, const int* __restrict__ batch,
                       float* __restrict__ pool_sum, float* __restrict__ pool_max,
                       int* __restrict__ pool_cnt){
    __shared__ float ssum[256], smax[256];
    int b = blockIdx.x;            // graph id
    int t = threadIdx.x;           // 0..255
    int lo = lower_bound_batch(batch, b);
    int hi = lower_bound_batch(batch, b + 1);
    int c = t & 63;                // channel
    int j = t >> 6;                // node slice 0..3
    float s = 0.f, mx = -INFINITY;
    for (int nd = lo + j; nd < hi; nd += 4){
        float v = h2[(size_t)nd * C2 + c];
        s += v;
        mx = fmaxf(mx, v);
    }
    ssum[t] = s; smax[t] = mx;
    __syncthreads();
    if (t < 128){ ssum[t] += ssum[t + 128]; smax[t] = fmaxf(smax[t], smax[t + 128]); }
    __syncthreads();
    if (t < 64){
        pool_sum[b * C2 + t] = ssum[t] + ssum[t + 64];
        pool_max[b * C2 + t] = fmaxf(smax[t], smax[t + 64]);
    }
    if (t == 0) pool_cnt[b] = hi - lo;
}

// ---------------- final linear [B,192]@[192,2] ----------------
__global__ void k_final(const float* __restrict__ pool_sum, const float* __restrict__ pool_max,
                        const int* __restrict__ pool_cnt,
                        const float* __restrict__ Wlin, const float* __restrict__ blin,
                        float* __restrict__ out){
    int t = threadIdx.x;
    if (t >= B_G * 2) return;
    int b = t >> 1, o = t & 1;
    float cnt = fmaxf((float)pool_cnt[b], 1.f);
    float acc = blin[o];
    for (int j = 0; j < C2; j++){
        float sm = pool_sum[b * C2 + j];
        float mx = pool_max[b * C2 + j];
        acc += (sm / cnt) * Wlin[j * 2 + o];
        acc += mx * Wlin[(C2 + j) * 2 + o];
        acc += sm * Wlin[(2 * C2 + j) * 2 + o];
    }
    out[b * 2 + o] = acc;
}

extern "C" void kernel_launch(void* const* d_in, const int* in_sizes, int n_in,
                              void* d_out, int out_size, void* d_ws, size_t ws_size,
                              hipStream_t stream) {
    const float* x     = (const float*)d_in[0];
    const int*   ei    = (const int*)d_in[1];
    const int*   batch = (const int*)d_in[2];
    const float* Wl1   = (const float*)d_in[3];
    const float* bl1   = (const float*)d_in[4];
    const float* Wr1   = (const float*)d_in[5];
    const float* br1   = (const float*)d_in[6];
    const float* att1  = (const float*)d_in[7];
    const float* bias1 = (const float*)d_in[8];
    const float* Wl2   = (const float*)d_in[9];
    const float* bl2   = (const float*)d_in[10];
    const float* Wr2   = (const float*)d_in[11];
    const float* br2   = (const float*)d_in[12];
    const float* att2  = (const float*)d_in[13];
    const float* bias2 = (const float*)d_in[14];
    const float* Wlin  = (const float*)d_in[15];
    const float* blin  = (const float*)d_in[16];
    float* out = (float*)d_out;

    char* w = (char*)d_ws;
    float* bufA = (float*)w;  w += (size_t)N_NODES * D1 * 4;   // xl1 ; later xl2|xr2
    float* bufB = (float*)w;  w += (size_t)N_NODES * D1 * 4;   // xr1 -> h1 ; later h2
    int* deg    = (int*)w;    w += (size_t)N_NODES * 4;
    int* row_ptr= (int*)w;    w += (size_t)(N_NODES + 1) * 4;
    int* cursor = (int*)w;    w += (size_t)N_NODES * 4;
    int* csr_src= (int*)w;    w += (size_t)ETOT * 4;
    int* part   = (int*)w;    w += (size_t)SCAN_NB * 4;
    float* pool_sum = (float*)w;  w += (size_t)B_G * C2 * 4;
    float* pool_max = (float*)w;  w += (size_t)B_G * C2 * 4;
    int*   pool_cnt = (int*)w;    w += (size_t)B_G * 4;

    float* xl1 = bufA;
    float* xr1 = bufB;
    float* h1  = bufB;                              // conv1 writes over xr1 (safe: dst-indexed)
    float* xl2 = bufA;                              // overwrites xl1 (dead after conv1)
    float* xr2 = bufA + (size_t)N_NODES * C2;
    float* h2  = bufB;                              // overwrites h1 (dead after lin2)

    // init deg
    k_init<<<(N_NODES + 255) / 256, 256, 0, stream>>>(deg);
    // conv1 linear
    k_lin1<<<N_NODES, 256, 0, stream>>>(x, Wl1, bl1, Wr1, br1, xl1, xr1);
    // CSR build (shared by both convs) — parallel two-level scan
    k_deg<<<(ETOT + 255) / 256, 256, 0, stream>>>(ei, deg);
    k_scan1<<<SCAN_NB, 256, 0, stream>>>(deg, part);
    k_scan2<<<1, 64, 0, stream>>>(part);
    k_scan3<<<SCAN_NB, 256, 0, stream>>>(deg, part, row_ptr, cursor);
    k_fill<<<(ETOT + 255) / 256, 256, 0, stream>>>(ei, cursor, csr_src);
    // conv1 fused (att + softmax + agg + ELU)
    k_conv1<<<N_NODES, 256, 0, stream>>>(row_ptr, csr_src, xl1, xr1, att1, bias1, h1);
    // conv2
    k_lin2<<<N_NODES / LIN2_NB, 256, 0, stream>>>(h1, Wl2, bl2, Wr2, br2, xl2, xr2);
    k_conv2<<<(N_NODES + 3) / 4, 256, 0, stream>>>(row_ptr, csr_src, xl2, xr2, att2, bias2, h2);
    // pooling (atomic-free) + head
    k_pool<<<B_G, 256, 0, stream>>>(h2, batch, pool_sum, pool_max, pool_cnt);
    k_final<<<1, 128, 0, stream>>>(pool_sum, pool_max, pool_cnt, Wlin, blin, out);
}